// Round 1
// baseline (7419.865 us; speedup 1.0000x reference)
//
#include <hip/hip_runtime.h>
#include <math.h>

// ---------------- problem constants ----------------
#define BATCH   2
#define CIN     1024
#define COUT    1024
#define HH      50
#define WW      84
#define HWX     4200          // 50*84
#define NA      15
#define NSC     63000         // HWX*NA
#define TOPN    2000
#define POSTN   300
#define CAP     8192          // candidate capacity for top-k sort
#define CLS_OFF   0           // floats into d_out
#define BBOX_OFF  252000      // 2*30*4200
#define ROIS_OFF  756000      // + 2*60*4200
#define PROBS_OFF 759000      // + 600*5

__constant__ double ANCH[NA][4] = {
  {-15.0,  -4.0,  30.0, 19.0},
  {-38.0, -16.0,  53.0, 31.0},
  {-84.0, -40.0,  99.0, 55.0},
  {-176.0,-88.0, 191.0,103.0},
  {-360.0,-184.0,375.0,199.0},
  {-8.0,  -8.0,  23.0, 23.0},
  {-24.0, -24.0, 39.0, 39.0},
  {-56.0, -56.0, 71.0, 71.0},
  {-120.0,-120.0,135.0,135.0},
  {-248.0,-248.0,263.0,263.0},
  {-3.0, -14.0, 18.0, 29.0},
  {-14.0, -36.0, 29.0, 51.0},
  {-36.0, -80.0, 51.0, 95.0},
  {-80.0,-168.0, 95.0,183.0},
  {-168.0,-344.0,183.0,359.0}
};

#define BBOX_CLIP 4.1351665567423560     // log(1000/16) in double

// ================= K1: 3x3 conv + bias + relu, fp64 accumulate =================
// block: 256 thr; tile: 4 rows x 16 cols spatial, 64 out-channels; K-chunk 16.
// LDS: x-halo staged as f64 (converted once), weights fp32 with stride-65 pad.
__launch_bounds__(256)
__global__ void conv3x3_k(const float* __restrict__ xin,
                          const float* __restrict__ wcv,
                          const float* __restrict__ bias,
                          float* __restrict__ hout) {
  __shared__ double XH[16*6*18];        // [ci][yy(6)][xx(18)]  13.8 KB
  __shared__ float  W9[16*9*65];        // [(ci*9+tap)*65 + co] 37.4 KB
  const int tid = threadIdx.x;
  const int sid = blockIdx.x;           // 0..155
  const int b   = sid / 78;
  const int s   = sid % 78;
  const int y0  = (s / 6) * 4;
  const int x0  = (s % 6) * 16;
  const int n0  = blockIdx.y * 64;
  const int tidN = tid & 15;            // 16 co-groups
  const int tidM = tid >> 4;            // 16 pos-groups
  const int py   = tidM >> 2;           // row within tile
  const int px0  = (tidM & 3) * 4;      // col base within tile

  double acc[4][4];                     // [x-pos][co]
  #pragma unroll
  for (int i = 0; i < 4; ++i)
    #pragma unroll
    for (int j = 0; j < 4; ++j) acc[i][j] = 0.0;

  for (int c0 = 0; c0 < CIN; c0 += 16) {
    // ---- stage x halo tile (zero padded) as f64 ----
    for (int e = tid; e < 1728; e += 256) {
      int ci = e / 108; int r = e - ci*108;
      int yy = r / 18;  int xx = r - yy*18;
      int gy = y0 + yy - 1, gx = x0 + xx - 1;
      float v = 0.f;
      if ((unsigned)gy < (unsigned)HH && (unsigned)gx < (unsigned)WW)
        v = xin[((size_t)(b*CIN + c0 + ci)*HH + gy)*WW + gx];
      XH[e] = (double)v;
    }
    // ---- stage weights: global reads are 144-float contiguous runs per co ----
    for (int e = tid; e < 9216; e += 256) {
      int co = e / 144; int r = e - co*144;
      int ci = r / 9;   int tap = r - ci*9;
      W9[(ci*9 + tap)*65 + co] = wcv[(size_t)(n0 + co)*9216 + (c0 + ci)*9 + tap];
    }
    __syncthreads();

    #pragma unroll 1
    for (int tap = 0; tap < 9; ++tap) {
      const int dy = tap / 3, dx = tap - 3*(tap/3);
      const double* Ap = XH + (py + dy)*18 + px0 + dx;
      const float*  Bp = W9 + tap*65 + tidN*4;
      #pragma unroll
      for (int ci = 0; ci < 16; ++ci) {
        double a0 = Ap[ci*108+0], a1 = Ap[ci*108+1], a2 = Ap[ci*108+2], a3 = Ap[ci*108+3];
        double b0 = (double)Bp[ci*585+0];
        double b1 = (double)Bp[ci*585+1];
        double b2 = (double)Bp[ci*585+2];
        double b3 = (double)Bp[ci*585+3];
        acc[0][0] += a0*b0; acc[0][1] += a0*b1; acc[0][2] += a0*b2; acc[0][3] += a0*b3;
        acc[1][0] += a1*b0; acc[1][1] += a1*b1; acc[1][2] += a1*b2; acc[1][3] += a1*b3;
        acc[2][0] += a2*b0; acc[2][1] += a2*b1; acc[2][2] += a2*b2; acc[2][3] += a2*b3;
        acc[3][0] += a3*b0; acc[3][1] += a3*b1; acc[3][2] += a3*b2; acc[3][3] += a3*b3;
      }
    }
    __syncthreads();
  }

  const int yg = y0 + py;
  const int xg = x0 + px0;
  if (yg < HH && xg < WW) {             // x positions are all-or-none valid (W%4==0)
    #pragma unroll
    for (int j = 0; j < 4; ++j) {
      int co = n0 + tidN*4 + j;
      double bv = (double)bias[co];
      float4 o;
      o.x = (float)fmax(acc[0][j] + bv, 0.0);
      o.y = (float)fmax(acc[1][j] + bv, 0.0);
      o.z = (float)fmax(acc[2][j] + bv, 0.0);
      o.w = (float)fmax(acc[3][j] + bv, 0.0);
      *(float4*)&hout[((size_t)(b*COUT + co)*HH + yg)*WW + xg] = o;
    }
  }
}

// ================= K2a: transpose head weights to [c][96] =================
__global__ void wt_k(const float* __restrict__ cls_w, const float* __restrict__ bbox_w,
                     float* __restrict__ wT) {
  int t = blockIdx.x*256 + threadIdx.x;
  if (t >= 96*1024) return;
  int c = t / 96, o = t - (t/96)*96;
  float v = 0.f;
  if (o < 30)      v = cls_w[(size_t)o*1024 + c];
  else if (o < 90) v = bbox_w[(size_t)(o-30)*1024 + c];
  wT[t] = v;
}

// ================= K2: fused 1x1 heads (cls 30 + bbox 60), fp64 acc =================
__launch_bounds__(256)
__global__ void heads_k(const float* __restrict__ h, const float* __restrict__ wT,
                        const float* __restrict__ cls_b, const float* __restrict__ bbox_b,
                        float* __restrict__ out_cls, float* __restrict__ out_bbox) {
  __shared__ float Hs[32*64];   // [ci][mi]
  __shared__ float Ws[32*96];   // [ci][o]
  const int tid = threadIdx.x;
  const int b   = blockIdx.y;
  const int m0  = blockIdx.x * 64;
  const int tp  = tid & 15;     // 4 positions each
  const int to  = tid >> 4;     // 6 outputs each (16*6=96)

  double acc[4][6];
  #pragma unroll
  for (int i = 0; i < 4; ++i)
    #pragma unroll
    for (int j = 0; j < 6; ++j) acc[i][j] = 0.0;

  for (int c0 = 0; c0 < CIN; c0 += 32) {
    for (int e = tid; e < 2048; e += 256) {
      int ci = e >> 6, mi = e & 63; int m = m0 + mi;
      Hs[e] = (m < HWX) ? h[((size_t)b*COUT + c0 + ci)*HWX + m] : 0.f;
    }
    for (int e = tid; e < 3072; e += 256) {
      int ci = e / 96, o = e - ci*96;
      Ws[e] = wT[(size_t)(c0 + ci)*96 + o];
    }
    __syncthreads();
    #pragma unroll 8
    for (int ci = 0; ci < 32; ++ci) {
      double a[4], w[6];
      #pragma unroll
      for (int i = 0; i < 4; ++i) a[i] = (double)Hs[ci*64 + tp*4 + i];
      #pragma unroll
      for (int j = 0; j < 6; ++j) w[j] = (double)Ws[ci*96 + to*6 + j];
      #pragma unroll
      for (int i = 0; i < 4; ++i)
        #pragma unroll
        for (int j = 0; j < 6; ++j) acc[i][j] += a[i]*w[j];
    }
    __syncthreads();
  }

  const int mb = m0 + tp*4;
  if (mb < HWX) {                         // all-or-none (HWX%4==0)
    #pragma unroll
    for (int j = 0; j < 6; ++j) {
      int o = to*6 + j;
      if (o < 30) {
        double bv = (double)cls_b[o];
        float4 v;
        v.x=(float)(acc[0][j]+bv); v.y=(float)(acc[1][j]+bv);
        v.z=(float)(acc[2][j]+bv); v.w=(float)(acc[3][j]+bv);
        *(float4*)&out_cls[((size_t)(b*30 + o))*HWX + mb] = v;
      } else if (o < 90) {
        int ob = o - 30;
        double bv = (double)bbox_b[ob];
        float4 v;
        v.x=(float)(acc[0][j]+bv); v.y=(float)(acc[1][j]+bv);
        v.z=(float)(acc[2][j]+bv); v.w=(float)(acc[3][j]+bv);
        *(float4*)&out_bbox[((size_t)(b*60 + ob))*HWX + mb] = v;
      }
    }
  }
}

// ================= K2b: scores = sigmoid(l1-l0), fp64 interior =================
__global__ void score_k(const float* __restrict__ out_cls, float* __restrict__ scores) {
  int t = blockIdx.x*256 + threadIdx.x;
  if (t >= BATCH*NSC) return;
  int b = t / NSC; int r = t - b*NSC;
  int m = r / NA;  int a = r - m*NA;
  float l0 = out_cls[((size_t)(b*30 + a))*HWX + m];
  float l1 = out_cls[((size_t)(b*30 + a + NA))*HWX + m];
  double p = 1.0 / (1.0 + exp((double)l0 - (double)l1));
  scores[t] = (float)p;
}

// ================= K3: per-image top-2000 (radix select + bitonic), stable ties =================
__launch_bounds__(1024)
__global__ void topk_k(const float* __restrict__ scores,
                       unsigned* __restrict__ top_idx, float* __restrict__ top_score) {
  __shared__ unsigned hist[256];
  __shared__ unsigned sh_b1, sh_need, sh_cut, sh_cnt;
  __shared__ unsigned long long key[CAP];
  const int b = blockIdx.x;
  const int tid = threadIdx.x;
  const float* sc = scores + (size_t)b*NSC;

  if (tid < 256) hist[tid] = 0;
  __syncthreads();
  for (int i = tid; i < NSC; i += 1024) {
    unsigned k = __float_as_uint(sc[i]);
    atomicAdd(&hist[k >> 24], 1u);
  }
  __syncthreads();
  if (tid == 0) {
    unsigned cum = 0; int bin = 255;
    for (; bin >= 0; --bin) { cum += hist[bin]; if (cum >= TOPN) break; }
    sh_b1 = (unsigned)bin;
    sh_need = TOPN - (cum - hist[bin]);
  }
  __syncthreads();
  const unsigned b1 = sh_b1, need = sh_need;
  if (tid < 256) hist[tid] = 0;
  __syncthreads();
  for (int i = tid; i < NSC; i += 1024) {
    unsigned k = __float_as_uint(sc[i]);
    if ((k >> 24) == b1) atomicAdd(&hist[(k >> 16) & 255u], 1u);
  }
  __syncthreads();
  if (tid == 0) {
    unsigned cum = 0; int bin = 255;
    for (; bin >= 0; --bin) { cum += hist[bin]; if (cum >= need) break; }
    sh_cut = (b1 << 8) | (unsigned)bin;
    sh_cnt = 0;
  }
  __syncthreads();
  const unsigned cut = sh_cut;
  for (int i = tid; i < CAP; i += 1024) key[i] = 0ull;
  __syncthreads();
  for (int i = tid; i < NSC; i += 1024) {
    unsigned k = __float_as_uint(sc[i]);
    if ((k >> 16) >= cut) {
      unsigned p = atomicAdd(&sh_cnt, 1u);
      if (p < CAP)
        key[p] = ((unsigned long long)k << 32) | (unsigned long long)(0xFFFFFFFFu - (unsigned)i);
    }
  }
  __syncthreads();
  // bitonic sort, DESCENDING by (score_bits, -idx)
  for (int k2 = 2; k2 <= CAP; k2 <<= 1) {
    for (int j = k2 >> 1; j > 0; j >>= 1) {
      for (int i = tid; i < CAP; i += 1024) {
        int p = i ^ j;
        if (p > i) {
          unsigned long long a = key[i], c = key[p];
          bool up = ((i & k2) == 0);
          if (up ? (a < c) : (a > c)) { key[i] = c; key[p] = a; }
        }
      }
      __syncthreads();
    }
  }
  for (int i = tid; i < TOPN; i += 1024) {
    unsigned long long kk = key[i];
    top_idx[(size_t)b*TOPN + i]   = 0xFFFFFFFFu - (unsigned)(kk & 0xFFFFFFFFull);
    top_score[(size_t)b*TOPN + i] = __uint_as_float((unsigned)(kk >> 32));
  }
}

// ================= K4: decode + clip top boxes (fp64) =================
__global__ void decode_k(const unsigned* __restrict__ top_idx,
                         const float* __restrict__ out_bbox,
                         const float* __restrict__ im_info,
                         double* __restrict__ boxesd) {
  int t = blockIdx.x*256 + threadIdx.x;
  if (t >= BATCH*TOPN) return;
  int b = t / TOPN;
  unsigned idx = top_idx[t];
  int a = idx % NA; int m = idx / NA;
  int yy = m / WW;  int xx = m - yy*WW;
  double sx = (double)xx * 16.0, sy = (double)yy * 16.0;
  double A0 = ANCH[a][0] + sx, A1 = ANCH[a][1] + sy;
  double A2 = ANCH[a][2] + sx, A3 = ANCH[a][3] + sy;
  double w_ = A2 - A0 + 1.0, h_ = A3 - A1 + 1.0;
  double cx = A0 + 0.5*w_,  cy = A1 + 0.5*h_;
  const float* bp = out_bbox + (size_t)b*60*HWX;
  double dx = (double)bp[(a*4+0)*HWX + m];
  double dy = (double)bp[(a*4+1)*HWX + m];
  double dw = fmin((double)bp[(a*4+2)*HWX + m], BBOX_CLIP);
  double dh = fmin((double)bp[(a*4+3)*HWX + m], BBOX_CLIP);
  double pcx = dx*w_ + cx, pcy = dy*h_ + cy;
  double pw = exp(dw)*w_,  ph = exp(dh)*h_;
  double x1 = pcx - 0.5*pw, y1 = pcy - 0.5*ph;
  double x2 = pcx + 0.5*pw - 1.0, y2 = pcy + 0.5*ph - 1.0;
  double hmax = (double)im_info[b*3+0] - 1.0;
  double wmax = (double)im_info[b*3+1] - 1.0;
  x1 = fmin(fmax(x1, 0.0), wmax); x2 = fmin(fmax(x2, 0.0), wmax);
  y1 = fmin(fmax(y1, 0.0), hmax); y2 = fmin(fmax(y2, 0.0), hmax);
  boxesd[(size_t)t*4+0] = x1; boxesd[(size_t)t*4+1] = y1;
  boxesd[(size_t)t*4+2] = x2; boxesd[(size_t)t*4+3] = y2;
}

// ================= K5: IoU suppression bitmask (fp64) =================
__launch_bounds__(256)
__global__ void iou_k(const double* __restrict__ boxesd,
                      unsigned long long* __restrict__ mask) {
  __shared__ double BX[TOPN*4];    // 64 KB
  const int b  = blockIdx.y;
  const int i0 = blockIdx.x * 8;
  const double* src = boxesd + (size_t)b*TOPN*4;
  for (int e = threadIdx.x; e < TOPN*4; e += 256) BX[e] = src[e];
  __syncthreads();
  const int il = threadIdx.x >> 5;
  const int w  = threadIdx.x & 31;
  const int i  = i0 + il;
  double x1 = BX[i*4+0], y1 = BX[i*4+1], x2 = BX[i*4+2], y2 = BX[i*4+3];
  double ai = (x2 - x1 + 1.0)*(y2 - y1 + 1.0);
  unsigned long long bits = 0ull;
  for (int jj = 0; jj < 64; ++jj) {
    int j = w*64 + jj;
    if (j >= TOPN) break;
    double bx1 = BX[j*4+0], by1 = BX[j*4+1], bx2 = BX[j*4+2], by2 = BX[j*4+3];
    double xx1 = fmax(x1, bx1), yy1 = fmax(y1, by1);
    double xx2 = fmin(x2, bx2), yy2 = fmin(y2, by2);
    double iw = fmax(xx2 - xx1 + 1.0, 0.0);
    double ih = fmax(yy2 - yy1 + 1.0, 0.0);
    double inter = iw * ih;
    double aj = (bx2 - bx1 + 1.0)*(by2 - by1 + 1.0);
    double iou = inter / (ai + aj - inter);
    if (iou > 0.7) bits |= (1ull << jj);
  }
  mask[((size_t)b*TOPN + i)*32 + w] = bits;
}

// ================= K6: serial NMS scan + prefix + emit rois/probs =================
__launch_bounds__(256)
__global__ void nms_out_k(const unsigned long long* __restrict__ mask,
                          const double* __restrict__ boxesd,
                          const float* __restrict__ top_score,
                          float* __restrict__ rois, float* __restrict__ probs) {
  __shared__ unsigned long long MS[256*32];  // 64 KB chunk of mask rows
  __shared__ unsigned keepf[2048];
  __shared__ unsigned psum[256];
  const int b = blockIdx.x;
  const int tid = threadIdx.x;
  for (int i = tid; i < 2048; i += 256) keepf[i] = 0;

  unsigned long long acc = 0ull;             // lanes 0..31 of wave 0
  for (int ch = 0; ch < 8; ++ch) {
    const int base = ch * 256;
    __syncthreads();
    for (int e = tid; e < 256*32; e += 256) {
      int row = base + (e >> 5);
      MS[e] = (row < TOPN) ? mask[((size_t)b*TOPN + row)*32 + (e & 31)] : 0ull;
    }
    __syncthreads();
    if (tid < 64) {
      const int lane = tid;
      for (int r = 0; r < 256; ++r) {
        int i = base + r;
        if (i >= TOPN) break;
        unsigned long long wv = __shfl(acc, i >> 6);
        if (!((wv >> (i & 63)) & 1ull)) {
          if (lane == 0) keepf[i] = 1;
          if (lane < 32) acc |= MS[r*32 + lane];
        }
      }
    }
  }
  __syncthreads();

  // prefix sum over keepf[0..1999]; thread t owns indices t*8..t*8+7
  const int base0 = tid * 8;
  unsigned lsum = 0;
  #pragma unroll
  for (int q = 0; q < 8; ++q) { int i = base0 + q; if (i < TOPN) lsum += keepf[i]; }
  psum[tid] = lsum;
  __syncthreads();
  for (int off = 1; off < 256; off <<= 1) {
    unsigned v = (tid >= off) ? psum[tid - off] : 0u;
    __syncthreads();
    psum[tid] += v;
    __syncthreads();
  }
  unsigned rank = (tid == 0) ? 0u : psum[tid - 1];

  // zero-init all rows (coords + probs), batch id column
  for (int j = tid; j < POSTN; j += 256) {
    float* rr = rois + ((size_t)b*POSTN + j)*5;
    rr[0] = (float)b; rr[1] = 0.f; rr[2] = 0.f; rr[3] = 0.f; rr[4] = 0.f;
    probs[(size_t)b*POSTN + j] = 0.f;
  }
  __syncthreads();

  for (int q = 0; q < 8; ++q) {
    int i = base0 + q;
    if (i < TOPN && keepf[i]) {
      if (rank < POSTN) {
        const double* bx = boxesd + ((size_t)b*TOPN + i)*4;
        float* rr = rois + ((size_t)b*POSTN + rank)*5;
        rr[1] = (float)bx[0]; rr[2] = (float)bx[1];
        rr[3] = (float)bx[2]; rr[4] = (float)bx[3];
        probs[(size_t)b*POSTN + rank] = top_score[(size_t)b*TOPN + i];
      }
      rank++;
    }
  }
}

// ================= launch =================
extern "C" void kernel_launch(void* const* d_in, const int* in_sizes, int n_in,
                              void* d_out, int out_size, void* d_ws, size_t ws_size,
                              hipStream_t stream) {
  const float* x      = (const float*)d_in[0];
  const float* conv_w = (const float*)d_in[1];
  const float* conv_b = (const float*)d_in[2];
  const float* cls_w  = (const float*)d_in[3];
  const float* cls_b  = (const float*)d_in[4];
  const float* bbox_w = (const float*)d_in[5];
  const float* bbox_b = (const float*)d_in[6];
  const float* im_info= (const float*)d_in[7];

  float* out  = (float*)d_out;
  float* out_cls  = out + CLS_OFF;
  float* out_bbox = out + BBOX_OFF;
  float* rois     = out + ROIS_OFF;
  float* probs    = out + PROBS_OFF;

  // workspace layout (float-slot offsets; boxesd/mask 8B-aligned by construction)
  float* wsf = (float*)d_ws;
  float*    h       = wsf;                              // 8,601,600 f
  float*    wT      = wsf + 8601600;                    //   98,304 f
  float*    scores  = wsf + 8699904;                    //  126,000 f
  unsigned* top_idx = (unsigned*)(wsf + 8825904);       //    4,000 u32
  float*    top_sc  = wsf + 8829904;                    //    4,000 f
  double*   boxesd  = (double*)(wsf + 8833904);         //   16,000 f64 (32,000 slots)
  unsigned long long* mask = (unsigned long long*)(wsf + 8865904); // 128,000 u64

  wt_k<<<dim3((96*1024 + 255)/256), dim3(256), 0, stream>>>(cls_w, bbox_w, wT);
  conv3x3_k<<<dim3(156, 16), dim3(256), 0, stream>>>(x, conv_w, conv_b, h);
  heads_k<<<dim3(66, 2), dim3(256), 0, stream>>>(h, wT, cls_b, bbox_b, out_cls, out_bbox);
  score_k<<<dim3((BATCH*NSC + 255)/256), dim3(256), 0, stream>>>(out_cls, scores);
  topk_k<<<dim3(2), dim3(1024), 0, stream>>>(scores, top_idx, top_sc);
  decode_k<<<dim3((BATCH*TOPN + 255)/256), dim3(256), 0, stream>>>(top_idx, out_bbox, im_info, boxesd);
  iou_k<<<dim3(TOPN/8, 2), dim3(256), 0, stream>>>(boxesd, mask);
  nms_out_k<<<dim3(2), dim3(256), 0, stream>>>(mask, boxesd, top_sc, rois, probs);
}

// Round 3
// 5697.933 us; speedup vs baseline: 1.3022x; 1.3022x over previous
//
#include <hip/hip_runtime.h>
#include <math.h>

// ---------------- problem constants ----------------
#define BATCH   2
#define CIN     1024
#define COUT    1024
#define HH      50
#define WW      84
#define HWX     4200          // 50*84
#define NA      15
#define NSC     63000         // HWX*NA
#define TOPN    2000
#define POSTN   300
#define CAP     8192          // candidate capacity for top-k sort
#define CLS_OFF   0           // floats into d_out
#define BBOX_OFF  252000      // 2*30*4200
#define ROIS_OFF  756000      // + 2*60*4200
#define PROBS_OFF 759000      // + 600*5

__constant__ double ANCH[NA][4] = {
  {-15.0,  -4.0,  30.0, 19.0},
  {-38.0, -16.0,  53.0, 31.0},
  {-84.0, -40.0,  99.0, 55.0},
  {-176.0,-88.0, 191.0,103.0},
  {-360.0,-184.0,375.0,199.0},
  {-8.0,  -8.0,  23.0, 23.0},
  {-24.0, -24.0, 39.0, 39.0},
  {-56.0, -56.0, 71.0, 71.0},
  {-120.0,-120.0,135.0,135.0},
  {-248.0,-248.0,263.0,263.0},
  {-3.0, -14.0, 18.0, 29.0},
  {-14.0, -36.0, 29.0, 51.0},
  {-36.0, -80.0, 51.0, 95.0},
  {-80.0,-168.0, 95.0,183.0},
  {-168.0,-344.0,183.0,359.0}
};

#define BBOX_CLIP 4.1351665567423560     // log(1000/16) in double

// ================= K1: 3x3 conv + bias + relu, fp64 accumulate =================
// NUMERICS CONSTRAINT (R2 post-mortem): fp32 accumulation flips top-k/NMS
// ordering vs the np reference (rois absmax 443). Score path must be fp64.
//
// block 256 thr; tile 16 rows x 16 cols spatial, 32 couts; K-chunk 16.
// Per thread: 8 x-positions x 4 couts, fp64 acc (64 VGPRs).
// LDS fp32 (convert to f64 in regs): XH[16ci][18][20pad] = 23.0 KB,
// W9[144][36pad] = 20.7 KB -> 43.7 KB -> 3 blocks/CU; grid 1536 = 2x768 exact.
// All LDS reads aligned ds_read_b128, conflict-free (A: row stride 20 floats,
// 8 rows cover all 32 banks; W: 8 addrs x 16B = 128B, broadcast x8).
// Wave layout: wave = one col-group (8 px) x 8 rows x 8 co-groups ->
// fully-OOB waves (row/col overhang) skip the FMA loop entirely.
__launch_bounds__(256, 3)
__global__ void conv3x3_k(const float* __restrict__ xin,
                          const float* __restrict__ wcv,
                          const float* __restrict__ bias,
                          float* __restrict__ hout) {
  __shared__ __align__(16) float XH[16*18*20];   // [ci][yy18][xx20] 23.0 KB
  __shared__ __align__(16) float W9[144*36];     // [k=ci*9+tap][36pad] 20.7 KB
  const int tid = threadIdx.x;
  const int sid = blockIdx.x;            // 0..47: batch x 4 row-tiles x 6 col-tiles
  const int b   = sid / 24;
  const int s   = sid % 24;
  const int y0  = (s / 6) * 16;
  const int x0  = (s % 6) * 16;
  const int n0  = blockIdx.y * 32;

  const int cog = tid & 7;               // co-group: 4 consecutive couts
  const int p   = tid >> 3;              // pos-group 0..31
  const int row = p & 15;                // row within tile
  const int cg  = p >> 4;                // col half (8 px each)
  const int cob = cog * 4;
  const int px0 = cg * 8;

  // wave-uniform skip: this wave's 8 rows all OOB, or its col half all OOB
  const bool skip = ((y0 + (row & ~7)) >= HH) || ((x0 + px0) >= WW);

  // W staging: thread -> (co, float4-phase)
  const int wco = tid & 31;
  const int wq  = tid >> 5;

  double acc[8][4];
  #pragma unroll
  for (int i = 0; i < 8; ++i)
    #pragma unroll
    for (int j = 0; j < 4; ++j) acc[i][j] = 0.0;

  for (int c0 = 0; c0 < CIN; c0 += 16) {
    // ---- stage x halo tile (zero padded), rows 18, cols 18 (pad to 20) ----
    for (int e = tid; e < 5760; e += 256) {
      int ci = e / 360; int r = e - ci*360;
      int yy = r / 20;  int xx = r - yy*20;
      int gy = y0 + yy - 1, gx = x0 + xx - 1;
      float v = 0.f;
      if (xx < 18 && (unsigned)gy < (unsigned)HH && (unsigned)gx < (unsigned)WW)
        v = xin[((size_t)(b*CIN + c0 + ci)*HH + gy)*WW + gx];
      XH[e] = v;
    }
    // ---- stage weights: float4 global reads (144 contiguous floats per co) ----
    {
      const float4* wp = (const float4*)wcv + (size_t)(n0 + wco)*2304 + (size_t)(c0/16)*36;
      for (int v = wq; v < 36; v += 8) {
        float4 w4 = wp[v];
        int k = 4*v;
        W9[(k+0)*36 + wco] = w4.x;
        W9[(k+1)*36 + wco] = w4.y;
        W9[(k+2)*36 + wco] = w4.z;
        W9[(k+3)*36 + wco] = w4.w;
      }
    }
    __syncthreads();

    if (!skip) {
      #pragma unroll 1
      for (int ci = 0; ci < 16; ++ci) {
        #pragma unroll
        for (int dy = 0; dy < 3; ++dy) {
          const float4* Ar = (const float4*)(XH + (ci*18 + row + dy)*20 + px0);
          float4 a4a = Ar[0], a4b = Ar[1], a4c = Ar[2];
          double av[12];
          av[0]=a4a.x; av[1]=a4a.y; av[2]=a4a.z; av[3]=a4a.w;
          av[4]=a4b.x; av[5]=a4b.y; av[6]=a4b.z; av[7]=a4b.w;
          av[8]=a4c.x; av[9]=a4c.y; av[10]=a4c.z; av[11]=a4c.w;
          #pragma unroll
          for (int dx = 0; dx < 3; ++dx) {
            const float4* Bp = (const float4*)(W9 + (ci*9 + dy*3 + dx)*36 + cob);
            float4 w4 = Bp[0];
            double w0 = (double)w4.x, w1 = (double)w4.y;
            double w2 = (double)w4.z, w3 = (double)w4.w;
            #pragma unroll
            for (int i = 0; i < 8; ++i) {
              double a = av[i + dx];
              acc[i][0] += a*w0; acc[i][1] += a*w1;
              acc[i][2] += a*w2; acc[i][3] += a*w3;
            }
          }
        }
      }
    }
    __syncthreads();
  }

  const int yg = y0 + row;
  const int xg = x0 + px0;
  if (!skip && yg < HH) {
    #pragma unroll
    for (int j = 0; j < 4; ++j) {
      int co = n0 + cob + j;
      double bv = (double)bias[co];
      float o[8];
      #pragma unroll
      for (int i = 0; i < 8; ++i) o[i] = (float)fmax(acc[i][j] + bv, 0.0);
      float* dst = &hout[((size_t)(b*COUT + co)*HH + yg)*WW + xg];
      if (xg + 4 <= WW) { float4 v0 = {o[0],o[1],o[2],o[3]}; *(float4*)dst = v0; }
      if (xg + 8 <= WW) { float4 v1 = {o[4],o[5],o[6],o[7]}; *(float4*)(dst+4) = v1; }
    }
  }
}

// ================= K2a: transpose head weights to [c][96] =================
__global__ void wt_k(const float* __restrict__ cls_w, const float* __restrict__ bbox_w,
                     float* __restrict__ wT) {
  int t = blockIdx.x*256 + threadIdx.x;
  if (t >= 96*1024) return;
  int c = t / 96, o = t - (t/96)*96;
  float v = 0.f;
  if (o < 30)      v = cls_w[(size_t)o*1024 + c];
  else if (o < 90) v = bbox_w[(size_t)(o-30)*1024 + c];
  wT[t] = v;
}

// ================= K2: fused 1x1 heads (cls 30 + bbox 60), fp64 acc =================
__launch_bounds__(256)
__global__ void heads_k(const float* __restrict__ h, const float* __restrict__ wT,
                        const float* __restrict__ cls_b, const float* __restrict__ bbox_b,
                        float* __restrict__ out_cls, float* __restrict__ out_bbox) {
  __shared__ float Hs[32*64];   // [ci][mi]
  __shared__ float Ws[32*96];   // [ci][o]
  const int tid = threadIdx.x;
  const int b   = blockIdx.y;
  const int m0  = blockIdx.x * 64;
  const int tp  = tid & 15;     // 4 positions each
  const int to  = tid >> 4;     // 6 outputs each (16*6=96)

  double acc[4][6];
  #pragma unroll
  for (int i = 0; i < 4; ++i)
    #pragma unroll
    for (int j = 0; j < 6; ++j) acc[i][j] = 0.0;

  for (int c0 = 0; c0 < CIN; c0 += 32) {
    for (int e = tid; e < 2048; e += 256) {
      int ci = e >> 6, mi = e & 63; int m = m0 + mi;
      Hs[e] = (m < HWX) ? h[((size_t)b*COUT + c0 + ci)*HWX + m] : 0.f;
    }
    for (int e = tid; e < 3072; e += 256) {
      int ci = e / 96, o = e - ci*96;
      Ws[e] = wT[(size_t)(c0 + ci)*96 + o];
    }
    __syncthreads();
    #pragma unroll 8
    for (int ci = 0; ci < 32; ++ci) {
      double a[4], w[6];
      #pragma unroll
      for (int i = 0; i < 4; ++i) a[i] = (double)Hs[ci*64 + tp*4 + i];
      #pragma unroll
      for (int j = 0; j < 6; ++j) w[j] = (double)Ws[ci*96 + to*6 + j];
      #pragma unroll
      for (int i = 0; i < 4; ++i)
        #pragma unroll
        for (int j = 0; j < 6; ++j) acc[i][j] += a[i]*w[j];
    }
    __syncthreads();
  }

  const int mb = m0 + tp*4;
  if (mb < HWX) {                         // all-or-none (HWX%4==0)
    #pragma unroll
    for (int j = 0; j < 6; ++j) {
      int o = to*6 + j;
      if (o < 30) {
        double bv = (double)cls_b[o];
        float4 v;
        v.x=(float)(acc[0][j]+bv); v.y=(float)(acc[1][j]+bv);
        v.z=(float)(acc[2][j]+bv); v.w=(float)(acc[3][j]+bv);
        *(float4*)&out_cls[((size_t)(b*30 + o))*HWX + mb] = v;
      } else if (o < 90) {
        int ob = o - 30;
        double bv = (double)bbox_b[ob];
        float4 v;
        v.x=(float)(acc[0][j]+bv); v.y=(float)(acc[1][j]+bv);
        v.z=(float)(acc[2][j]+bv); v.w=(float)(acc[3][j]+bv);
        *(float4*)&out_bbox[((size_t)(b*60 + ob))*HWX + mb] = v;
      }
    }
  }
}

// ================= K2b: scores = sigmoid(l1-l0), fp64 interior =================
__global__ void score_k(const float* __restrict__ out_cls, float* __restrict__ scores) {
  int t = blockIdx.x*256 + threadIdx.x;
  if (t >= BATCH*NSC) return;
  int b = t / NSC; int r = t - b*NSC;
  int m = r / NA;  int a = r - m*NA;
  float l0 = out_cls[((size_t)(b*30 + a))*HWX + m];
  float l1 = out_cls[((size_t)(b*30 + a + NA))*HWX + m];
  double p = 1.0 / (1.0 + exp((double)l0 - (double)l1));
  scores[t] = (float)p;
}

// ================= K3: per-image top-2000 (radix select + bitonic), stable ties =================
__launch_bounds__(1024)
__global__ void topk_k(const float* __restrict__ scores,
                       unsigned* __restrict__ top_idx, float* __restrict__ top_score) {
  __shared__ unsigned hist[256];
  __shared__ unsigned sh_b1, sh_need, sh_cut, sh_cnt;
  __shared__ unsigned long long key[CAP];
  const int b = blockIdx.x;
  const int tid = threadIdx.x;
  const float* sc = scores + (size_t)b*NSC;

  if (tid < 256) hist[tid] = 0;
  __syncthreads();
  for (int i = tid; i < NSC; i += 1024) {
    unsigned k = __float_as_uint(sc[i]);
    atomicAdd(&hist[k >> 24], 1u);
  }
  __syncthreads();
  if (tid == 0) {
    unsigned cum = 0; int bin = 255;
    for (; bin >= 0; --bin) { cum += hist[bin]; if (cum >= TOPN) break; }
    sh_b1 = (unsigned)bin;
    sh_need = TOPN - (cum - hist[bin]);
  }
  __syncthreads();
  const unsigned b1 = sh_b1, need = sh_need;
  if (tid < 256) hist[tid] = 0;
  __syncthreads();
  for (int i = tid; i < NSC; i += 1024) {
    unsigned k = __float_as_uint(sc[i]);
    if ((k >> 24) == b1) atomicAdd(&hist[(k >> 16) & 255u], 1u);
  }
  __syncthreads();
  if (tid == 0) {
    unsigned cum = 0; int bin = 255;
    for (; bin >= 0; --bin) { cum += hist[bin]; if (cum >= need) break; }
    sh_cut = (b1 << 8) | (unsigned)bin;
    sh_cnt = 0;
  }
  __syncthreads();
  const unsigned cut = sh_cut;
  for (int i = tid; i < CAP; i += 1024) key[i] = 0ull;
  __syncthreads();
  for (int i = tid; i < NSC; i += 1024) {
    unsigned k = __float_as_uint(sc[i]);
    if ((k >> 16) >= cut) {
      unsigned p = atomicAdd(&sh_cnt, 1u);
      if (p < CAP)
        key[p] = ((unsigned long long)k << 32) | (unsigned long long)(0xFFFFFFFFu - (unsigned)i);
    }
  }
  __syncthreads();
  // bitonic sort, DESCENDING by (score_bits, -idx)
  for (int k2 = 2; k2 <= CAP; k2 <<= 1) {
    for (int j = k2 >> 1; j > 0; j >>= 1) {
      for (int i = tid; i < CAP; i += 1024) {
        int p = i ^ j;
        if (p > i) {
          unsigned long long a = key[i], c = key[p];
          bool up = ((i & k2) == 0);
          if (up ? (a < c) : (a > c)) { key[i] = c; key[p] = a; }
        }
      }
      __syncthreads();
    }
  }
  for (int i = tid; i < TOPN; i += 1024) {
    unsigned long long kk = key[i];
    top_idx[(size_t)b*TOPN + i]   = 0xFFFFFFFFu - (unsigned)(kk & 0xFFFFFFFFull);
    top_score[(size_t)b*TOPN + i] = __uint_as_float((unsigned)(kk >> 32));
  }
}

// ================= K4: decode + clip top boxes (fp64) =================
__global__ void decode_k(const unsigned* __restrict__ top_idx,
                         const float* __restrict__ out_bbox,
                         const float* __restrict__ im_info,
                         double* __restrict__ boxesd) {
  int t = blockIdx.x*256 + threadIdx.x;
  if (t >= BATCH*TOPN) return;
  int b = t / TOPN;
  unsigned idx = top_idx[t];
  int a = idx % NA; int m = idx / NA;
  int yy = m / WW;  int xx = m - yy*WW;
  double sx = (double)xx * 16.0, sy = (double)yy * 16.0;
  double A0 = ANCH[a][0] + sx, A1 = ANCH[a][1] + sy;
  double A2 = ANCH[a][2] + sx, A3 = ANCH[a][3] + sy;
  double w_ = A2 - A0 + 1.0, h_ = A3 - A1 + 1.0;
  double cx = A0 + 0.5*w_,  cy = A1 + 0.5*h_;
  const float* bp = out_bbox + (size_t)b*60*HWX;
  double dx = (double)bp[(a*4+0)*HWX + m];
  double dy = (double)bp[(a*4+1)*HWX + m];
  double dw = fmin((double)bp[(a*4+2)*HWX + m], BBOX_CLIP);
  double dh = fmin((double)bp[(a*4+3)*HWX + m], BBOX_CLIP);
  double pcx = dx*w_ + cx, pcy = dy*h_ + cy;
  double pw = exp(dw)*w_,  ph = exp(dh)*h_;
  double x1 = pcx - 0.5*pw, y1 = pcy - 0.5*ph;
  double x2 = pcx + 0.5*pw - 1.0, y2 = pcy + 0.5*ph - 1.0;
  double hmax = (double)im_info[b*3+0] - 1.0;
  double wmax = (double)im_info[b*3+1] - 1.0;
  x1 = fmin(fmax(x1, 0.0), wmax); x2 = fmin(fmax(x2, 0.0), wmax);
  y1 = fmin(fmax(y1, 0.0), hmax); y2 = fmin(fmax(y2, 0.0), hmax);
  boxesd[(size_t)t*4+0] = x1; boxesd[(size_t)t*4+1] = y1;
  boxesd[(size_t)t*4+2] = x2; boxesd[(size_t)t*4+3] = y2;
}

// ================= K5: IoU suppression bitmask (fp64) =================
__launch_bounds__(256)
__global__ void iou_k(const double* __restrict__ boxesd,
                      unsigned long long* __restrict__ mask) {
  __shared__ double BX[TOPN*4];    // 64 KB
  const int b  = blockIdx.y;
  const int i0 = blockIdx.x * 8;
  const double* src = boxesd + (size_t)b*TOPN*4;
  for (int e = threadIdx.x; e < TOPN*4; e += 256) BX[e] = src[e];
  __syncthreads();
  const int il = threadIdx.x >> 5;
  const int w  = threadIdx.x & 31;
  const int i  = i0 + il;
  double x1 = BX[i*4+0], y1 = BX[i*4+1], x2 = BX[i*4+2], y2 = BX[i*4+3];
  double ai = (x2 - x1 + 1.0)*(y2 - y1 + 1.0);
  unsigned long long bits = 0ull;
  for (int jj = 0; jj < 64; ++jj) {
    int j = w*64 + jj;
    if (j >= TOPN) break;
    double bx1 = BX[j*4+0], by1 = BX[j*4+1], bx2 = BX[j*4+2], by2 = BX[j*4+3];
    double xx1 = fmax(x1, bx1), yy1 = fmax(y1, by1);
    double xx2 = fmin(x2, bx2), yy2 = fmin(y2, by2);
    double iw = fmax(xx2 - xx1 + 1.0, 0.0);
    double ih = fmax(yy2 - yy1 + 1.0, 0.0);
    double inter = iw * ih;
    double aj = (bx2 - bx1 + 1.0)*(by2 - by1 + 1.0);
    double iou = inter / (ai + aj - inter);
    if (iou > 0.7) bits |= (1ull << jj);
  }
  mask[((size_t)b*TOPN + i)*32 + w] = bits;
}

// ================= K6: serial NMS scan + prefix + emit rois/probs =================
__launch_bounds__(256)
__global__ void nms_out_k(const unsigned long long* __restrict__ mask,
                          const double* __restrict__ boxesd,
                          const float* __restrict__ top_score,
                          float* __restrict__ rois, float* __restrict__ probs) {
  __shared__ unsigned long long MS[256*32];  // 64 KB chunk of mask rows
  __shared__ unsigned keepf[2048];
  __shared__ unsigned psum[256];
  const int b = blockIdx.x;
  const int tid = threadIdx.x;
  for (int i = tid; i < 2048; i += 256) keepf[i] = 0;

  unsigned long long acc = 0ull;             // lanes 0..31 of wave 0
  for (int ch = 0; ch < 8; ++ch) {
    const int base = ch * 256;
    __syncthreads();
    for (int e = tid; e < 256*32; e += 256) {
      int row = base + (e >> 5);
      MS[e] = (row < TOPN) ? mask[((size_t)b*TOPN + row)*32 + (e & 31)] : 0ull;
    }
    __syncthreads();
    if (tid < 64) {
      const int lane = tid;
      for (int r = 0; r < 256; ++r) {
        int i = base + r;
        if (i >= TOPN) break;
        unsigned long long wv = __shfl(acc, i >> 6);
        if (!((wv >> (i & 63)) & 1ull)) {
          if (lane == 0) keepf[i] = 1;
          if (lane < 32) acc |= MS[r*32 + lane];
        }
      }
    }
  }
  __syncthreads();

  // prefix sum over keepf[0..1999]; thread t owns indices t*8..t*8+7
  const int base0 = tid * 8;
  unsigned lsum = 0;
  #pragma unroll
  for (int q = 0; q < 8; ++q) { int i = base0 + q; if (i < TOPN) lsum += keepf[i]; }
  psum[tid] = lsum;
  __syncthreads();
  for (int off = 1; off < 256; off <<= 1) {
    unsigned v = (tid >= off) ? psum[tid - off] : 0u;
    __syncthreads();
    psum[tid] += v;
    __syncthreads();
  }
  unsigned rank = (tid == 0) ? 0u : psum[tid - 1];

  // zero-init all rows (coords + probs), batch id column
  for (int j = tid; j < POSTN; j += 256) {
    float* rr = rois + ((size_t)b*POSTN + j)*5;
    rr[0] = (float)b; rr[1] = 0.f; rr[2] = 0.f; rr[3] = 0.f; rr[4] = 0.f;
    probs[(size_t)b*POSTN + j] = 0.f;
  }
  __syncthreads();

  for (int q = 0; q < 8; ++q) {
    int i = base0 + q;
    if (i < TOPN && keepf[i]) {
      if (rank < POSTN) {
        const double* bx = boxesd + ((size_t)b*TOPN + i)*4;
        float* rr = rois + ((size_t)b*POSTN + rank)*5;
        rr[1] = (float)bx[0]; rr[2] = (float)bx[1];
        rr[3] = (float)bx[2]; rr[4] = (float)bx[3];
        probs[(size_t)b*POSTN + rank] = top_score[(size_t)b*TOPN + i];
      }
      rank++;
    }
  }
}

// ================= launch =================
extern "C" void kernel_launch(void* const* d_in, const int* in_sizes, int n_in,
                              void* d_out, int out_size, void* d_ws, size_t ws_size,
                              hipStream_t stream) {
  const float* x      = (const float*)d_in[0];
  const float* conv_w = (const float*)d_in[1];
  const float* conv_b = (const float*)d_in[2];
  const float* cls_w  = (const float*)d_in[3];
  const float* cls_b  = (const float*)d_in[4];
  const float* bbox_w = (const float*)d_in[5];
  const float* bbox_b = (const float*)d_in[6];
  const float* im_info= (const float*)d_in[7];

  float* out  = (float*)d_out;
  float* out_cls  = out + CLS_OFF;
  float* out_bbox = out + BBOX_OFF;
  float* rois     = out + ROIS_OFF;
  float* probs    = out + PROBS_OFF;

  // workspace layout (float-slot offsets; boxesd/mask 8B-aligned by construction)
  float* wsf = (float*)d_ws;
  float*    h       = wsf;                              // 8,601,600 f
  float*    wT      = wsf + 8601600;                    //   98,304 f
  float*    scores  = wsf + 8699904;                    //  126,000 f
  unsigned* top_idx = (unsigned*)(wsf + 8825904);       //    4,000 u32
  float*    top_sc  = wsf + 8829904;                    //    4,000 f
  double*   boxesd  = (double*)(wsf + 8833904);         //   16,000 f64 (32,000 slots)
  unsigned long long* mask = (unsigned long long*)(wsf + 8865904); // 128,000 u64

  wt_k<<<dim3((96*1024 + 255)/256), dim3(256), 0, stream>>>(cls_w, bbox_w, wT);
  conv3x3_k<<<dim3(48, 32), dim3(256), 0, stream>>>(x, conv_w, conv_b, h);
  heads_k<<<dim3(66, 2), dim3(256), 0, stream>>>(h, wT, cls_b, bbox_b, out_cls, out_bbox);
  score_k<<<dim3((BATCH*NSC + 255)/256), dim3(256), 0, stream>>>(out_cls, scores);
  topk_k<<<dim3(2), dim3(1024), 0, stream>>>(scores, top_idx, top_sc);
  decode_k<<<dim3((BATCH*TOPN + 255)/256), dim3(256), 0, stream>>>(top_idx, out_bbox, im_info, boxesd);
  iou_k<<<dim3(TOPN/8, 2), dim3(256), 0, stream>>>(boxesd, mask);
  nms_out_k<<<dim3(2), dim3(256), 0, stream>>>(mask, boxesd, top_sc, rois, probs);
}

// Round 6
// 4317.245 us; speedup vs baseline: 1.7187x; 1.3198x over previous
//
#include <hip/hip_runtime.h>
#include <math.h>

// ---------------- problem constants ----------------
#define BATCH   2
#define CIN     1024
#define COUT    1024
#define HH      50
#define WW      84
#define HWX     4200          // 50*84
#define NA      15
#define NSC     63000         // HWX*NA
#define TOPN    2000
#define POSTN   300
#define CAP     8192          // candidate capacity for top-k sort
#define CLS_OFF   0           // floats into d_out
#define BBOX_OFF  252000      // 2*30*4200
#define ROIS_OFF  756000      // + 2*60*4200
#define PROBS_OFF 759000      // + 600*5

__constant__ double ANCH[NA][4] = {
  {-15.0,  -4.0,  30.0, 19.0},
  {-38.0, -16.0,  53.0, 31.0},
  {-84.0, -40.0,  99.0, 55.0},
  {-176.0,-88.0, 191.0,103.0},
  {-360.0,-184.0,375.0,199.0},
  {-8.0,  -8.0,  23.0, 23.0},
  {-24.0, -24.0, 39.0, 39.0},
  {-56.0, -56.0, 71.0, 71.0},
  {-120.0,-120.0,135.0,135.0},
  {-248.0,-248.0,263.0,263.0},
  {-3.0, -14.0, 18.0, 29.0},
  {-14.0, -36.0, 29.0, 51.0},
  {-36.0, -80.0, 51.0, 95.0},
  {-80.0,-168.0, 95.0,183.0},
  {-168.0,-344.0,183.0,359.0}
};

#define BBOX_CLIP 4.1351665567423560     // log(1000/16) in double

typedef double dx4 __attribute__((ext_vector_type(4)));

// ================= K1: 3x3 conv + bias + relu, f64 MFMA =================
// NUMERICS CONSTRAINT (R2): score path must be fp64-accurate or top-k/NMS
// ordering flips vs the np reference (only output 2 / rois is a real gate).
// R5 post-mortem: all indices audited clean under the ASSUMED f64 fragment
// layouts; f64 16x16x4 is NOT among the guide's verified cells. This round
// the epilogue is made layout-proof: two data-independent probe MFMAs
// (A=row-labels x B=ones, A=ones x B=col-labels) recover, for each
// (lane, reg), which position-label and cout-label that D element holds —
// correct under ANY row/col permutation (incl. transposed D). Remaining
// assumption: A and B share the k = lane/16 grouping (symmetric roles).
//
// Implicit GEMM: M = 16 positions/wave (2 rows x 8 cols), N = 64 couts
// (4 mfma N-tiles), K = 4 consecutive ci per mfma, x 9 taps x 16ci/stage.
// Block 256 = 4 waves: block tile 8 rows x 8 cols x 64 co.
// LDS: XH[16ci][10rows][12pad] 7.68 KB + W9[144][72pad] 41.47 KB = 48 KB
// -> 3 blocks/CU.
__launch_bounds__(256, 3)
__global__ void conv3x3_k(const float* __restrict__ xin,
                          const float* __restrict__ wcv,
                          const float* __restrict__ bias,
                          float* __restrict__ hout) {
  __shared__ __align__(16) float XH[16*120];   // [ci][yy10][xx12]
  __shared__ __align__(16) float W9[144*72];   // [tap*16+ci][co64 pad72]
  const int tid  = threadIdx.x;
  const int lane = tid & 63;
  const int w    = tid >> 6;           // wave id = row-pair within tile
  const int sid  = blockIdx.x;         // 0..153 = b(2) x ry(7) x cx(11)
  const int b    = sid / 77;
  const int s    = sid % 77;
  const int ry   = s / 11, cx = s % 11;
  const int y0   = ry * 8, x0 = cx * 8;
  const int n0   = blockIdx.y * 64;

  const int q    = lane >> 4;          // k-slice index
  const int m16  = lane & 15;          // position label (A) / cout label (B)
  const int laneA = q*120 + (2*w + (m16 >> 3))*12 + (lane & 7);
  const int laneB = q*72 + m16;
  const bool skip = (y0 + 2*w) >= HH;  // wave's both rows OOB

  // ---- D-layout probe (data independent): pidx = position label held by
  // (this lane, reg i); nidx = cout label. Exact small-int f64 arithmetic.
  int pidx[4], nidx[4];
  {
    dx4 pr = {0.,0.,0.,0.}, pc = {0.,0.,0.,0.};
    pr = __builtin_amdgcn_mfma_f64_16x16x4f64((double)m16, 1.0, pr, 0, 0, 0);
    pc = __builtin_amdgcn_mfma_f64_16x16x4f64(1.0, (double)m16, pc, 0, 0, 0);
    #pragma unroll
    for (int i = 0; i < 4; ++i) {
      pidx[i] = ((int)pr[i]) >> 2;     // value = 4 * label
      nidx[i] = ((int)pc[i]) >> 2;
    }
  }

  // weight staging: 4 consecutive lanes read consecutive float4s of one co
  const int wco = tid >> 2;            // 0..63
  const int wq  = tid & 3;

  dx4 acc[4] = {{0.,0.,0.,0.},{0.,0.,0.,0.},{0.,0.,0.,0.},{0.,0.,0.,0.}};

  for (int st = 0; st < 64; ++st) {
    // ---- stage x halo (zero-padded): 16 ci x 10 rows x 10 cols (pad 12) ----
    for (int e = tid; e < 1920; e += 256) {
      int ci = e / 120; int r = e - ci*120;
      int yy = r / 12;  int xx = r - yy*12;
      int gy = y0 + yy - 1, gx = x0 + xx - 1;
      float v = 0.f;
      if (xx < 10 && (unsigned)gy < (unsigned)HH && (unsigned)gx < (unsigned)WW)
        v = xin[((size_t)(b*CIN + st*16 + ci)*HH + gy)*WW + gx];
      XH[e] = v;
    }
    // ---- stage weights: 64 co x 144 floats; coalesced float4 runs per co ----
    {
      const float4* wp = (const float4*)wcv + (size_t)(n0 + wco)*2304 + (size_t)st*36;
      #pragma unroll
      for (int i = 0; i < 9; ++i) {
        float4 w4 = wp[wq*9 + i];
        int k4 = 4*(wq*9 + i);
        int k;
        k = k4+0; W9[((k%9)*16 + k/9)*72 + wco] = w4.x;
        k = k4+1; W9[((k%9)*16 + k/9)*72 + wco] = w4.y;
        k = k4+2; W9[((k%9)*16 + k/9)*72 + wco] = w4.z;
        k = k4+3; W9[((k%9)*16 + k/9)*72 + wco] = w4.w;
      }
    }
    __syncthreads();

    if (!skip) {
      const float* XA = XH + laneA;
      const float* WB = W9 + laneB;
      #pragma unroll
      for (int g = 0; g < 4; ++g) {          // ci groups of 4
        #pragma unroll
        for (int dy = 0; dy < 3; ++dy) {
          #pragma unroll
          for (int dx = 0; dx < 3; ++dx) {
            double a = (double)XA[g*480 + dy*12 + dx];
            const int tp = dy*3 + dx;
            double b0 = (double)WB[tp*1152 + g*288 +  0];
            double b1 = (double)WB[tp*1152 + g*288 + 16];
            double b2 = (double)WB[tp*1152 + g*288 + 32];
            double b3 = (double)WB[tp*1152 + g*288 + 48];
            acc[0] = __builtin_amdgcn_mfma_f64_16x16x4f64(a, b0, acc[0], 0, 0, 0);
            acc[1] = __builtin_amdgcn_mfma_f64_16x16x4f64(a, b1, acc[1], 0, 0, 0);
            acc[2] = __builtin_amdgcn_mfma_f64_16x16x4f64(a, b2, acc[2], 0, 0, 0);
            acc[3] = __builtin_amdgcn_mfma_f64_16x16x4f64(a, b3, acc[3], 0, 0, 0);
          }
        }
      }
    }
    __syncthreads();
  }

  // ---- layout-proof epilogue: scatter via probed labels ----
  if (!skip) {
    #pragma unroll
    for (int i = 0; i < 4; ++i) {
      const int yg = y0 + 2*w + (pidx[i] >> 3);   // <= 49 when !skip
      const int xg = x0 + (pidx[i] & 7);
      if (xg < WW) {
        #pragma unroll
        for (int nt = 0; nt < 4; ++nt) {
          int co = n0 + nt*16 + nidx[i];
          double bv = (double)bias[co];
          hout[((size_t)(b*COUT + co)*HH + yg)*WW + xg] =
              (float)fmax(acc[nt][i] + bv, 0.0);
        }
      }
    }
  }
}

// ================= K2a: transpose head weights to [c][96] =================
__global__ void wt_k(const float* __restrict__ cls_w, const float* __restrict__ bbox_w,
                     float* __restrict__ wT) {
  int t = blockIdx.x*256 + threadIdx.x;
  if (t >= 96*1024) return;
  int c = t / 96, o = t - (t/96)*96;
  float v = 0.f;
  if (o < 30)      v = cls_w[(size_t)o*1024 + c];
  else if (o < 90) v = bbox_w[(size_t)(o-30)*1024 + c];
  wT[t] = v;
}

// ================= K2: fused 1x1 heads (cls 30 + bbox 60), fp64 acc =================
__launch_bounds__(256)
__global__ void heads_k(const float* __restrict__ h, const float* __restrict__ wT,
                        const float* __restrict__ cls_b, const float* __restrict__ bbox_b,
                        float* __restrict__ out_cls, float* __restrict__ out_bbox) {
  __shared__ float Hs[32*64];   // [ci][mi]
  __shared__ float Ws[32*96];   // [ci][o]
  const int tid = threadIdx.x;
  const int b   = blockIdx.y;
  const int m0  = blockIdx.x * 64;
  const int tp  = tid & 15;     // 4 positions each
  const int to  = tid >> 4;     // 6 outputs each (16*6=96)

  double acc[4][6];
  #pragma unroll
  for (int i = 0; i < 4; ++i)
    #pragma unroll
    for (int j = 0; j < 6; ++j) acc[i][j] = 0.0;

  for (int c0 = 0; c0 < CIN; c0 += 32) {
    for (int e = tid; e < 2048; e += 256) {
      int ci = e >> 6, mi = e & 63; int m = m0 + mi;
      Hs[e] = (m < HWX) ? h[((size_t)b*COUT + c0 + ci)*HWX + m] : 0.f;
    }
    for (int e = tid; e < 3072; e += 256) {
      int ci = e / 96, o = e - ci*96;
      Ws[e] = wT[(size_t)(c0 + ci)*96 + o];
    }
    __syncthreads();
    #pragma unroll 8
    for (int ci = 0; ci < 32; ++ci) {
      double a[4], wv[6];
      #pragma unroll
      for (int i = 0; i < 4; ++i) a[i] = (double)Hs[ci*64 + tp*4 + i];
      #pragma unroll
      for (int j = 0; j < 6; ++j) wv[j] = (double)Ws[ci*96 + to*6 + j];
      #pragma unroll
      for (int i = 0; i < 4; ++i)
        #pragma unroll
        for (int j = 0; j < 6; ++j) acc[i][j] += a[i]*wv[j];
    }
    __syncthreads();
  }

  const int mb = m0 + tp*4;
  if (mb < HWX) {                         // all-or-none (HWX%4==0)
    #pragma unroll
    for (int j = 0; j < 6; ++j) {
      int o = to*6 + j;
      if (o < 30) {
        double bv = (double)cls_b[o];
        float4 v;
        v.x=(float)(acc[0][j]+bv); v.y=(float)(acc[1][j]+bv);
        v.z=(float)(acc[2][j]+bv); v.w=(float)(acc[3][j]+bv);
        *(float4*)&out_cls[((size_t)(b*30 + o))*HWX + mb] = v;
      } else if (o < 90) {
        int ob = o - 30;
        double bv = (double)bbox_b[ob];
        float4 v;
        v.x=(float)(acc[0][j]+bv); v.y=(float)(acc[1][j]+bv);
        v.z=(float)(acc[2][j]+bv); v.w=(float)(acc[3][j]+bv);
        *(float4*)&out_bbox[((size_t)(b*60 + ob))*HWX + mb] = v;
      }
    }
  }
}

// ================= K2b: scores = sigmoid(l1-l0), fp64 interior =================
__global__ void score_k(const float* __restrict__ out_cls, float* __restrict__ scores) {
  int t = blockIdx.x*256 + threadIdx.x;
  if (t >= BATCH*NSC) return;
  int b = t / NSC; int r = t - b*NSC;
  int m = r / NA;  int a = r - m*NA;
  float l0 = out_cls[((size_t)(b*30 + a))*HWX + m];
  float l1 = out_cls[((size_t)(b*30 + a + NA))*HWX + m];
  double p = 1.0 / (1.0 + exp((double)l0 - (double)l1));
  scores[t] = (float)p;
}

// ================= K3: per-image top-2000 (radix select + bitonic), stable ties =================
__launch_bounds__(1024)
__global__ void topk_k(const float* __restrict__ scores,
                       unsigned* __restrict__ top_idx, float* __restrict__ top_score) {
  __shared__ unsigned hist[256];
  __shared__ unsigned sh_b1, sh_need, sh_cut, sh_cnt;
  __shared__ unsigned long long key[CAP];
  const int b = blockIdx.x;
  const int tid = threadIdx.x;
  const float* sc = scores + (size_t)b*NSC;

  if (tid < 256) hist[tid] = 0;
  __syncthreads();
  for (int i = tid; i < NSC; i += 1024) {
    unsigned k = __float_as_uint(sc[i]);
    atomicAdd(&hist[k >> 24], 1u);
  }
  __syncthreads();
  if (tid == 0) {
    unsigned cum = 0; int bin = 255;
    for (; bin >= 0; --bin) { cum += hist[bin]; if (cum >= TOPN) break; }
    sh_b1 = (unsigned)bin;
    sh_need = TOPN - (cum - hist[bin]);
  }
  __syncthreads();
  const unsigned b1 = sh_b1, need = sh_need;
  if (tid < 256) hist[tid] = 0;
  __syncthreads();
  for (int i = tid; i < NSC; i += 1024) {
    unsigned k = __float_as_uint(sc[i]);
    if ((k >> 24) == b1) atomicAdd(&hist[(k >> 16) & 255u], 1u);
  }
  __syncthreads();
  if (tid == 0) {
    unsigned cum = 0; int bin = 255;
    for (; bin >= 0; --bin) { cum += hist[bin]; if (cum >= need) break; }
    sh_cut = (b1 << 8) | (unsigned)bin;
    sh_cnt = 0;
  }
  __syncthreads();
  const unsigned cut = sh_cut;
  for (int i = tid; i < CAP; i += 1024) key[i] = 0ull;
  __syncthreads();
  for (int i = tid; i < NSC; i += 1024) {
    unsigned k = __float_as_uint(sc[i]);
    if ((k >> 16) >= cut) {
      unsigned p = atomicAdd(&sh_cnt, 1u);
      if (p < CAP)
        key[p] = ((unsigned long long)k << 32) | (unsigned long long)(0xFFFFFFFFu - (unsigned)i);
    }
  }
  __syncthreads();
  // bitonic sort, DESCENDING by (score_bits, -idx)
  for (int k2 = 2; k2 <= CAP; k2 <<= 1) {
    for (int j = k2 >> 1; j > 0; j >>= 1) {
      for (int i = tid; i < CAP; i += 1024) {
        int p = i ^ j;
        if (p > i) {
          unsigned long long a = key[i], c = key[p];
          bool up = ((i & k2) == 0);
          if (up ? (a < c) : (a > c)) { key[i] = c; key[p] = a; }
        }
      }
      __syncthreads();
    }
  }
  for (int i = tid; i < TOPN; i += 1024) {
    unsigned long long kk = key[i];
    top_idx[(size_t)b*TOPN + i]   = 0xFFFFFFFFu - (unsigned)(kk & 0xFFFFFFFFull);
    top_score[(size_t)b*TOPN + i] = __uint_as_float((unsigned)(kk >> 32));
  }
}

// ================= K4: decode + clip top boxes (fp64) =================
__global__ void decode_k(const unsigned* __restrict__ top_idx,
                         const float* __restrict__ out_bbox,
                         const float* __restrict__ im_info,
                         double* __restrict__ boxesd) {
  int t = blockIdx.x*256 + threadIdx.x;
  if (t >= BATCH*TOPN) return;
  int b = t / TOPN;
  unsigned idx = top_idx[t];
  int a = idx % NA; int m = idx / NA;
  int yy = m / WW;  int xx = m - yy*WW;
  double sx = (double)xx * 16.0, sy = (double)yy * 16.0;
  double A0 = ANCH[a][0] + sx, A1 = ANCH[a][1] + sy;
  double A2 = ANCH[a][2] + sx, A3 = ANCH[a][3] + sy;
  double w_ = A2 - A0 + 1.0, h_ = A3 - A1 + 1.0;
  double cx = A0 + 0.5*w_,  cy = A1 + 0.5*h_;
  const float* bp = out_bbox + (size_t)b*60*HWX;
  double dx = (double)bp[(a*4+0)*HWX + m];
  double dy = (double)bp[(a*4+1)*HWX + m];
  double dw = fmin((double)bp[(a*4+2)*HWX + m], BBOX_CLIP);
  double dh = fmin((double)bp[(a*4+3)*HWX + m], BBOX_CLIP);
  double pcx = dx*w_ + cx, pcy = dy*h_ + cy;
  double pw = exp(dw)*w_,  ph = exp(dh)*h_;
  double x1 = pcx - 0.5*pw, y1 = pcy - 0.5*ph;
  double x2 = pcx + 0.5*pw - 1.0, y2 = pcy + 0.5*ph - 1.0;
  double hmax = (double)im_info[b*3+0] - 1.0;
  double wmax = (double)im_info[b*3+1] - 1.0;
  x1 = fmin(fmax(x1, 0.0), wmax); x2 = fmin(fmax(x2, 0.0), wmax);
  y1 = fmin(fmax(y1, 0.0), hmax); y2 = fmin(fmax(y2, 0.0), hmax);
  boxesd[(size_t)t*4+0] = x1; boxesd[(size_t)t*4+1] = y1;
  boxesd[(size_t)t*4+2] = x2; boxesd[(size_t)t*4+3] = y2;
}

// ================= K5: IoU suppression bitmask (fp64) =================
__launch_bounds__(256)
__global__ void iou_k(const double* __restrict__ boxesd,
                      unsigned long long* __restrict__ mask) {
  __shared__ double BX[TOPN*4];    // 64 KB
  const int b  = blockIdx.y;
  const int i0 = blockIdx.x * 8;
  const double* src = boxesd + (size_t)b*TOPN*4;
  for (int e = threadIdx.x; e < TOPN*4; e += 256) BX[e] = src[e];
  __syncthreads();
  const int il = threadIdx.x >> 5;
  const int w  = threadIdx.x & 31;
  const int i  = i0 + il;
  double x1 = BX[i*4+0], y1 = BX[i*4+1], x2 = BX[i*4+2], y2 = BX[i*4+3];
  double ai = (x2 - x1 + 1.0)*(y2 - y1 + 1.0);
  unsigned long long bits = 0ull;
  for (int jj = 0; jj < 64; ++jj) {
    int j = w*64 + jj;
    if (j >= TOPN) break;
    double bx1 = BX[j*4+0], by1 = BX[j*4+1], bx2 = BX[j*4+2], by2 = BX[j*4+3];
    double xx1 = fmax(x1, bx1), yy1 = fmax(y1, by1);
    double xx2 = fmin(x2, bx2), yy2 = fmin(y2, by2);
    double iw = fmax(xx2 - xx1 + 1.0, 0.0);
    double ih = fmax(yy2 - yy1 + 1.0, 0.0);
    double inter = iw * ih;
    double aj = (bx2 - bx1 + 1.0)*(by2 - by1 + 1.0);
    double iou = inter / (ai + aj - inter);
    if (iou > 0.7) bits |= (1ull << jj);
  }
  mask[((size_t)b*TOPN + i)*32 + w] = bits;
}

// ================= K6: serial NMS scan + prefix + emit rois/probs =================
__launch_bounds__(256)
__global__ void nms_out_k(const unsigned long long* __restrict__ mask,
                          const double* __restrict__ boxesd,
                          const float* __restrict__ top_score,
                          float* __restrict__ rois, float* __restrict__ probs) {
  __shared__ unsigned long long MS[256*32];  // 64 KB chunk of mask rows
  __shared__ unsigned keepf[2048];
  __shared__ unsigned psum[256];
  const int b = blockIdx.x;
  const int tid = threadIdx.x;
  for (int i = tid; i < 2048; i += 256) keepf[i] = 0;

  unsigned long long acc = 0ull;             // lanes 0..31 of wave 0
  for (int ch = 0; ch < 8; ++ch) {
    const int base = ch * 256;
    __syncthreads();
    for (int e = tid; e < 256*32; e += 256) {
      int row = base + (e >> 5);
      MS[e] = (row < TOPN) ? mask[((size_t)b*TOPN + row)*32 + (e & 31)] : 0ull;
    }
    __syncthreads();
    if (tid < 64) {
      const int lane = tid;
      for (int r = 0; r < 256; ++r) {
        int i = base + r;
        if (i >= TOPN) break;
        unsigned long long wv = __shfl(acc, i >> 6);
        if (!((wv >> (i & 63)) & 1ull)) {
          if (lane == 0) keepf[i] = 1;
          if (lane < 32) acc |= MS[r*32 + lane];
        }
      }
    }
  }
  __syncthreads();

  // prefix sum over keepf[0..1999]; thread t owns indices t*8..t*8+7
  const int base0 = tid * 8;
  unsigned lsum = 0;
  #pragma unroll
  for (int q = 0; q < 8; ++q) { int i = base0 + q; if (i < TOPN) lsum += keepf[i]; }
  psum[tid] = lsum;
  __syncthreads();
  for (int off = 1; off < 256; off <<= 1) {
    unsigned v = (tid >= off) ? psum[tid - off] : 0u;
    __syncthreads();
    psum[tid] += v;
    __syncthreads();
  }
  unsigned rank = (tid == 0) ? 0u : psum[tid - 1];

  // zero-init all rows (coords + probs), batch id column
  for (int j = tid; j < POSTN; j += 256) {
    float* rr = rois + ((size_t)b*POSTN + j)*5;
    rr[0] = (float)b; rr[1] = 0.f; rr[2] = 0.f; rr[3] = 0.f; rr[4] = 0.f;
    probs[(size_t)b*POSTN + j] = 0.f;
  }
  __syncthreads();

  for (int q = 0; q < 8; ++q) {
    int i = base0 + q;
    if (i < TOPN && keepf[i]) {
      if (rank < POSTN) {
        const double* bx = boxesd + ((size_t)b*TOPN + i)*4;
        float* rr = rois + ((size_t)b*POSTN + rank)*5;
        rr[1] = (float)bx[0]; rr[2] = (float)bx[1];
        rr[3] = (float)bx[2]; rr[4] = (float)bx[3];
        probs[(size_t)b*POSTN + rank] = top_score[(size_t)b*TOPN + i];
      }
      rank++;
    }
  }
}

// ================= launch =================
extern "C" void kernel_launch(void* const* d_in, const int* in_sizes, int n_in,
                              void* d_out, int out_size, void* d_ws, size_t ws_size,
                              hipStream_t stream) {
  const float* x      = (const float*)d_in[0];
  const float* conv_w = (const float*)d_in[1];
  const float* conv_b = (const float*)d_in[2];
  const float* cls_w  = (const float*)d_in[3];
  const float* cls_b  = (const float*)d_in[4];
  const float* bbox_w = (const float*)d_in[5];
  const float* bbox_b = (const float*)d_in[6];
  const float* im_info= (const float*)d_in[7];

  float* out  = (float*)d_out;
  float* out_cls  = out + CLS_OFF;
  float* out_bbox = out + BBOX_OFF;
  float* rois     = out + ROIS_OFF;
  float* probs    = out + PROBS_OFF;

  // workspace layout (float-slot offsets; boxesd/mask 8B-aligned by construction)
  float* wsf = (float*)d_ws;
  float*    h       = wsf;                              // 8,601,600 f
  float*    wT      = wsf + 8601600;                    //   98,304 f
  float*    scores  = wsf + 8699904;                    //  126,000 f
  unsigned* top_idx = (unsigned*)(wsf + 8825904);       //    4,000 u32
  float*    top_sc  = wsf + 8829904;                    //    4,000 f
  double*   boxesd  = (double*)(wsf + 8833904);         //   16,000 f64 (32,000 slots)
  unsigned long long* mask = (unsigned long long*)(wsf + 8865904); // 128,000 u64

  wt_k<<<dim3((96*1024 + 255)/256), dim3(256), 0, stream>>>(cls_w, bbox_w, wT);
  conv3x3_k<<<dim3(154, 16), dim3(256), 0, stream>>>(x, conv_w, conv_b, h);
  heads_k<<<dim3(66, 2), dim3(256), 0, stream>>>(h, wT, cls_b, bbox_b, out_cls, out_bbox);
  score_k<<<dim3((BATCH*NSC + 255)/256), dim3(256), 0, stream>>>(out_cls, scores);
  topk_k<<<dim3(2), dim3(1024), 0, stream>>>(scores, top_idx, top_sc);
  decode_k<<<dim3((BATCH*TOPN + 255)/256), dim3(256), 0, stream>>>(top_idx, out_bbox, im_info, boxesd);
  iou_k<<<dim3(TOPN/8, 2), dim3(256), 0, stream>>>(boxesd, mask);
  nms_out_k<<<dim3(2), dim3(256), 0, stream>>>(mask, boxesd, top_sc, rois, probs);
}